// Round 4
// baseline (795.467 us; speedup 1.0000x reference)
//
#include <hip/hip_runtime.h>
#include <hip/hip_cooperative_groups.h>
#include <math.h>

namespace cg = cooperative_groups;

#define DD 128
#define G 4              // steps batched per block (same level => node-disjoint => race-free)
#define TPB 512
#define NBLK_MAX 512
#define SMAX 2048

__device__ __forceinline__ float sigmoidf(float x) { return 1.0f / (1.0f + expf(-x)); }

// ---------------------------------------------------------------------------
// Predecessor kernel: block j scans i<j for last step sharing a node.
// ---------------------------------------------------------------------------
__global__ __launch_bounds__(64) void pred_kernel(
    const int* __restrict__ heads, const int* __restrict__ tails, int S,
    int* __restrict__ ph, int* __restrict__ pt) {
  const int j = blockIdx.x;
  if (j >= S) return;
  const int myh = heads[j], myt = tails[j];
  const int lane = threadIdx.x;
  int mph = -1, mpt = -1;
  for (int i = lane; i < j; i += 64) {
    int a = heads[i], b = tails[i];
    if (a == myh || b == myh) mph = i;
    if (a == myt || b == myt) mpt = i;
  }
#pragma unroll
  for (int off = 32; off > 0; off >>= 1) {
    mph = max(mph, __shfl_down(mph, off));
    mpt = max(mpt, __shfl_down(mpt, off));
  }
  if (lane == 0) { ph[j] = mph; pt[j] = mpt; }
}

// ---------------------------------------------------------------------------
// Finalize: fixpoint level relaxation + bucket by level.
// ---------------------------------------------------------------------------
__global__ __launch_bounds__(1024) void finalize_kernel(
    int S, const int* __restrict__ phg, const int* __restrict__ ptg,
    int* __restrict__ order, int* __restrict__ level_off, int* __restrict__ n_levels) {
  __shared__ int lvl[SMAX], ph[SMAX], pt[SMAX], cnt[SMAX];
  __shared__ int changed, maxl;
  const int tid = threadIdx.x;

  for (int j = tid; j < S; j += 1024) { ph[j] = phg[j]; pt[j] = ptg[j]; lvl[j] = 1; }
  __syncthreads();

  for (int it = 0; it < S + 2; ++it) {
    if (tid == 0) changed = 0;
    __syncthreads();
    for (int j = tid; j < S; j += 1024) {
      int l = 1;
      int a = ph[j]; if (a >= 0) l = lvl[a] + 1;
      int b = pt[j]; if (b >= 0) { int lb = lvl[b] + 1; if (lb > l) l = lb; }
      if (l != lvl[j]) { lvl[j] = l; changed = 1; }
    }
    __syncthreads();
    if (!changed) break;
    __syncthreads();
  }

  if (tid == 0) maxl = 0;
  __syncthreads();
  for (int j = tid; j < S; j += 1024) atomicMax(&maxl, lvl[j]);
  __syncthreads();
  const int M = maxl;

  for (int l = tid; l < M; l += 1024) cnt[l] = 0;
  __syncthreads();
  for (int j = tid; j < S; j += 1024) atomicAdd(&cnt[lvl[j] - 1], 1);
  __syncthreads();
  if (tid == 0) {
    int run = 0;
    level_off[0] = 0;
    for (int l = 0; l < M; ++l) { run += cnt[l]; level_off[l + 1] = run; }
    n_levels[0] = M;
  }
  __syncthreads();

  for (int l = tid; l < M; l += 1024) cnt[l] = 0;
  __syncthreads();
  for (int j = tid; j < S; j += 1024) {
    int lv = lvl[j] - 1;
    int pos = level_off[lv] + atomicAdd(&cnt[lv], 1);
    order[pos] = j;
  }
}

// ---------------------------------------------------------------------------
// Process kernel: G=4 same-level steps per block; weight loads amortized x4.
// LDS layout: activation arrays are [d][G] (stride 8 floats, float4-bcast reads).
// Overlays (phase-disjoint): {repH,repT,cHs,cTs} == {ZH,ZT}; {edgeH,edgeT} == {nhH,nhT}.
// ---------------------------------------------------------------------------
struct PParams {
  const int* heads; const int* tails; const float* times;
  float* node_rep; float* cell_head; float* hidden_head; float* cell_tail; float* hidden_tail;
  const float* Weh1; const float* Weh2; const float* beh;
  const float* Wet1; const float* Wet2; const float* bet;
  const float* Wxh; const float* Whh; const float* bh; const float* Wdh; const float* bdh;
  const float* Wxt; const float* Wht; const float* bt; const float* Wdt; const float* bdt;
  const float* Wc1; const float* Wc2;
  float* out; float* rt;
  const int* order; const int* level_off; const int* n_levels;
  int S;
};

__global__ __launch_bounds__(TPB) void process_kernel(PParams p) {
  cg::grid_group grid = cg::this_grid();
  const int tid = threadIdx.x;

  __shared__ __align__(16) float S_[12288];   // 48 KB
  __shared__ int sIdx[G], hIdx[G], tIdx[G];
  __shared__ float tmv[G], decHs[G], decTs[G];

  // float offsets into S_
  const int O_REPH = 0,    O_REPT = 1024, O_CHS = 2048, O_CTS = 3072;  // dead after A
  const int O_ZH   = 0,    O_ZT   = 2048;                              // born in B (overlay)
  const int O_HHS  = 4096, O_HTS  = 5120, O_HTH = 6144, O_HHT = 7168;  // persistent
  const int O_EH   = 8192, O_ET   = 9216;                              // edge (A..B) == nh (C..D)
  const int O_CAH  = 10240, O_CAT = 11264;                             // cadj (A..C)

  int nlv = p.n_levels[0];
  if (nlv < 0) nlv = 0;
  if (nlv > SMAX) nlv = SMAX;

  for (int lv = 0; lv < nlv; ++lv) {
    const int beg = p.level_off[lv], end = p.level_off[lv + 1];
    const int Lsz = end - beg;
    int gE = (Lsz + (int)gridDim.x - 1) / (int)gridDim.x;
    if (gE > G) gE = G;
    if (gE < 1) gE = 1;

    for (int base = beg + (int)blockIdx.x * gE; base < end; base += (int)gridDim.x * gE) {
      const int ng = min(gE, end - base);
      __syncthreads();   // protect previous iteration's LDS readers
      if (tid < ng) {
        int s = p.order[base + tid]; sIdx[tid] = s;
        int h = p.heads[s], t = p.tails[s];
        hIdx[tid] = h; tIdx[tid] = t;
        float tm = p.times[s]; tmv[tid] = tm;
        decHs[tid] = expf(-(tm - p.rt[h]));
        decTs[tid] = expf(-(tm - p.rt[t]));
      }
      __syncthreads();

      // -------- Gather: 8 node rows per step into [d][G] LDS + emit outputs
      {
        const int g = tid >> 7, d = tid & 127;
        if (g < ng) {
          const size_t oh = (size_t)hIdx[g] * DD + d;
          const size_t ot = (size_t)tIdx[g] * DD + d;
          const int b = d * 8 + g;
          float rh = p.node_rep[oh];
          S_[O_REPH + b] = rh; p.out[(size_t)sIdx[g] * DD + d] = rh;
          S_[O_CHS + b] = p.cell_head[oh];
          S_[O_HHS + b] = p.hidden_head[oh];
          S_[O_HTH + b] = p.hidden_tail[oh];
          float rt_ = p.node_rep[ot];
          S_[O_REPT + b] = rt_; p.out[(size_t)(p.S + sIdx[g]) * DD + d] = rt_;
          S_[O_CTS + b] = p.cell_tail[ot];
          S_[O_HTS + b] = p.hidden_tail[ot];
          S_[O_HHT + b] = p.hidden_head[ot];
        }
      }
      __syncthreads();

      // -------- Phase A: edges (roles 0,1) + decayed cell adjust (roles 2,3)
      {
        const int role = tid >> 7, e = tid & 127;
        if (role == 0) {
          float a0 = p.beh[e], a1 = a0, a2 = a0, a3 = a0;
          for (int d = 0; d < DD; ++d) {
            float w1 = p.Weh1[d * DD + e], w2 = p.Weh2[d * DD + e];
            float4 rh = *(const float4*)&S_[O_REPH + d * 8];
            float4 rt4 = *(const float4*)&S_[O_REPT + d * 8];
            a0 += rh.x * w1 + rt4.x * w2; a1 += rh.y * w1 + rt4.y * w2;
            a2 += rh.z * w1 + rt4.z * w2; a3 += rh.w * w1 + rt4.w * w2;
          }
          float4 o; o.x = tanhf(a0); o.y = tanhf(a1); o.z = tanhf(a2); o.w = tanhf(a3);
          *(float4*)&S_[O_EH + e * 8] = o;
        } else if (role == 1) {
          float a0 = p.bet[e], a1 = a0, a2 = a0, a3 = a0;
          for (int d = 0; d < DD; ++d) {
            float w1 = p.Wet1[d * DD + e], w2 = p.Wet2[d * DD + e];
            float4 rh = *(const float4*)&S_[O_REPH + d * 8];
            float4 rt4 = *(const float4*)&S_[O_REPT + d * 8];
            a0 += rh.x * w1 + rt4.x * w2; a1 += rh.y * w1 + rt4.y * w2;
            a2 += rh.z * w1 + rt4.z * w2; a3 += rh.w * w1 + rt4.w * w2;
          }
          float4 o; o.x = tanhf(a0); o.y = tanhf(a1); o.z = tanhf(a2); o.w = tanhf(a3);
          *(float4*)&S_[O_ET + e * 8] = o;
        } else if (role == 2) {
          float a0 = p.bdh[e], a1 = a0, a2 = a0, a3 = a0;
          for (int d = 0; d < DD; ++d) {
            float wd = p.Wdh[d * DD + e];
            float4 c4 = *(const float4*)&S_[O_CHS + d * 8];
            a0 += c4.x * wd; a1 += c4.y * wd; a2 += c4.z * wd; a3 += c4.w * wd;
          }
          float cs0 = tanhf(a0), cs1 = tanhf(a1), cs2 = tanhf(a2), cs3 = tanhf(a3);
          float4 o;
          o.x = S_[O_CHS + e * 8 + 0] - cs0 + cs0 * decHs[0];
          o.y = S_[O_CHS + e * 8 + 1] - cs1 + cs1 * decHs[1];
          o.z = S_[O_CHS + e * 8 + 2] - cs2 + cs2 * decHs[2];
          o.w = S_[O_CHS + e * 8 + 3] - cs3 + cs3 * decHs[3];
          *(float4*)&S_[O_CAH + e * 8] = o;
        } else {
          float a0 = p.bdt[e], a1 = a0, a2 = a0, a3 = a0;
          for (int d = 0; d < DD; ++d) {
            float wd = p.Wdt[d * DD + e];
            float4 c4 = *(const float4*)&S_[O_CTS + d * 8];
            a0 += c4.x * wd; a1 += c4.y * wd; a2 += c4.z * wd; a3 += c4.w * wd;
          }
          float cs0 = tanhf(a0), cs1 = tanhf(a1), cs2 = tanhf(a2), cs3 = tanhf(a3);
          float4 o;
          o.x = S_[O_CTS + e * 8 + 0] - cs0 + cs0 * decTs[0];
          o.y = S_[O_CTS + e * 8 + 1] - cs1 + cs1 * decTs[1];
          o.z = S_[O_CTS + e * 8 + 2] - cs2 + cs2 * decTs[2];
          o.w = S_[O_CTS + e * 8 + 3] - cs3 + cs3 * decTs[3];
          *(float4*)&S_[O_CAT + e * 8] = o;
        }
      }
      __syncthreads();

      // -------- Phase B: z = x@Wx + h@Wh + b, both sides, 1 col/thread, G accs
      {
        const int c = tid;
        float h0 = p.bh[c], h1 = h0, h2 = h0, h3 = h0;
        float t0 = p.bt[c], t1 = t0, t2 = t0, t3 = t0;
        for (int d = 0; d < DD; ++d) {
          float wxh = p.Wxh[d * 512 + c], whh = p.Whh[d * 512 + c];
          float wxt = p.Wxt[d * 512 + c], wht = p.Wht[d * 512 + c];
          float4 ex = *(const float4*)&S_[O_EH + d * 8];
          float4 hx = *(const float4*)&S_[O_HHS + d * 8];
          float4 et = *(const float4*)&S_[O_ET + d * 8];
          float4 ht4 = *(const float4*)&S_[O_HTS + d * 8];
          h0 += ex.x * wxh + hx.x * whh; h1 += ex.y * wxh + hx.y * whh;
          h2 += ex.z * wxh + hx.z * whh; h3 += ex.w * wxh + hx.w * whh;
          t0 += et.x * wxt + ht4.x * wht; t1 += et.y * wxt + ht4.y * wht;
          t2 += et.z * wxt + ht4.z * wht; t3 += et.w * wxt + ht4.w * wht;
        }
        float4 zh; zh.x = h0; zh.y = h1; zh.z = h2; zh.w = h3;
        float4 zt; zt.x = t0; zt.y = t1; zt.z = t2; zt.w = t3;
        *(float4*)&S_[O_ZH + c * 4] = zh;   // overlays rep/cHs (dead after A)
        *(float4*)&S_[O_ZT + c * 4] = zt;
      }
      __syncthreads();

      // -------- Phase C: gates, c/h update, scatter state, rt update
      {
        const int side = tid >> 8, sub = (tid >> 7) & 1, e = tid & 127;
        const int zo = side ? O_ZT : O_ZH;
        const int co = side ? O_CAT : O_CAH;
        const int no = side ? O_ET : O_EH;   // nh overlay on edge
        float* ctab = side ? p.cell_tail : p.cell_head;
        float* htab = side ? p.hidden_tail : p.hidden_head;
        for (int q = 0; q < 2; ++q) {
          int g = sub + 2 * q;
          if (g >= ng) continue;
          float iv = sigmoidf(S_[zo + e * 4 + g]);
          float fv = sigmoidf(S_[zo + (128 + e) * 4 + g]);
          float ov = sigmoidf(S_[zo + (256 + e) * 4 + g]);
          float gv = tanhf(S_[zo + (384 + e) * 4 + g]);
          float cadj = S_[co + e * 8 + g];
          float cn = fv * cadj + iv * gv;
          float hn = ov * tanhf(cn);
          S_[no + e * 8 + g] = hn;
          int node = side ? tIdx[g] : hIdx[g];
          ctab[(size_t)node * DD + e] = cn;
          htab[(size_t)node * DD + e] = hn;
        }
        if (tid < 2 * G) {
          int g = tid & (G - 1);
          if (g < ng) p.rt[(tid >= G) ? tIdx[g] : hIdx[g]] = tmv[g];
        }
      }
      __syncthreads();

      // -------- Phase D: combiner, rep scatter (tail wins on h==t)
      {
        const int role = tid >> 7, e = tid & 127;
        if (role == 0) {
          float a0 = 0.f, a1 = 0.f, a2 = 0.f, a3 = 0.f;
          for (int d = 0; d < DD; ++d) {
            float w1 = p.Wc1[d * DD + e], w2 = p.Wc2[d * DD + e];
            float4 x = *(const float4*)&S_[O_EH + d * 8];    // nhH
            float4 y = *(const float4*)&S_[O_HTH + d * 8];   // old hidden_tail[h]
            a0 += x.x * w1 + y.x * w2; a1 += x.y * w1 + y.y * w2;
            a2 += x.z * w1 + y.z * w2; a3 += x.w * w1 + y.w * w2;
          }
          float r[4] = {a0, a1, a2, a3};
          for (int g = 0; g < ng; ++g)
            if (hIdx[g] != tIdx[g])
              p.node_rep[(size_t)hIdx[g] * DD + e] = tanhf(r[g]);
        } else if (role == 1) {
          float a0 = 0.f, a1 = 0.f, a2 = 0.f, a3 = 0.f;
          for (int d = 0; d < DD; ++d) {
            float w1 = p.Wc1[d * DD + e], w2 = p.Wc2[d * DD + e];
            float4 x = *(const float4*)&S_[O_HHT + d * 8];   // old hidden_head[t] @ Wc1
            float4 y = *(const float4*)&S_[O_ET + d * 8];    // nhT @ Wc2
            a0 += x.x * w1 + y.x * w2; a1 += x.y * w1 + y.y * w2;
            a2 += x.z * w1 + y.z * w2; a3 += x.w * w1 + y.w * w2;
          }
          float r[4] = {a0, a1, a2, a3};
          for (int g = 0; g < ng; ++g)
            p.node_rep[(size_t)tIdx[g] * DD + e] = tanhf(r[g]);
        }
      }
    }
    __threadfence();
    grid.sync();
  }
}

// ---------------------------------------------------------------------------
extern "C" void kernel_launch(void* const* d_in, const int* in_sizes, int n_in,
                              void* d_out, int out_size, void* d_ws, size_t ws_size,
                              hipStream_t stream) {
  const int* heads = (const int*)d_in[0];
  const int* tails = (const int*)d_in[1];
  const float* times = (const float*)d_in[2];
  float* node_rep    = (float*)d_in[3];
  float* cell_head   = (float*)d_in[4];
  float* hidden_head = (float*)d_in[5];
  float* cell_tail   = (float*)d_in[6];
  float* hidden_tail = (float*)d_in[7];
  const float* Weh1 = (const float*)d_in[8];
  const float* Weh2 = (const float*)d_in[9];
  const float* beh  = (const float*)d_in[10];
  const float* Wet1 = (const float*)d_in[11];
  const float* Wet2 = (const float*)d_in[12];
  const float* bet  = (const float*)d_in[13];
  const float* Wxh  = (const float*)d_in[14];
  const float* Whh  = (const float*)d_in[15];
  const float* bh   = (const float*)d_in[16];
  const float* Wdh  = (const float*)d_in[17];
  const float* bdh  = (const float*)d_in[18];
  const float* Wxt  = (const float*)d_in[19];
  const float* Wht  = (const float*)d_in[20];
  const float* bt   = (const float*)d_in[21];
  const float* Wdt  = (const float*)d_in[22];
  const float* bdt  = (const float*)d_in[23];
  const float* Wc1  = (const float*)d_in[24];
  const float* Wc2  = (const float*)d_in[25];

  const int S = in_sizes[0];
  const int N = in_sizes[3] / DD;

  char* ws = (char*)d_ws;
  float* rt = (float*)ws;
  size_t rtBytes = (((size_t)N * 4) + 511) & ~(size_t)511;
  int* order     = (int*)(ws + rtBytes);
  int* level_off = order + SMAX;
  int* n_levels  = level_off + SMAX + 1;
  int* ph        = n_levels + 64;
  int* pt        = ph + SMAX;

  hipMemsetAsync(rt, 0, (size_t)N * 4, stream);
  pred_kernel<<<S, 64, 0, stream>>>(heads, tails, S, ph, pt);
  finalize_kernel<<<1, 1024, 0, stream>>>(S, ph, pt, order, level_off, n_levels);

  PParams p;
  p.heads = heads; p.tails = tails; p.times = times;
  p.node_rep = node_rep; p.cell_head = cell_head; p.hidden_head = hidden_head;
  p.cell_tail = cell_tail; p.hidden_tail = hidden_tail;
  p.Weh1 = Weh1; p.Weh2 = Weh2; p.beh = beh;
  p.Wet1 = Wet1; p.Wet2 = Wet2; p.bet = bet;
  p.Wxh = Wxh; p.Whh = Whh; p.bh = bh; p.Wdh = Wdh; p.bdh = bdh;
  p.Wxt = Wxt; p.Wht = Wht; p.bt = bt; p.Wdt = Wdt; p.bdt = bdt;
  p.Wc1 = Wc1; p.Wc2 = Wc2;
  p.out = (float*)d_out; p.rt = rt;
  p.order = order; p.level_off = level_off; p.n_levels = n_levels;
  p.S = S;

  void* args[] = { (void*)&p };

  // Coop grid sizing via runtime query (R2 lesson: never hard-code capacity).
  int dev = 0; hipGetDevice(&dev);
  int nCU = 0;
  hipDeviceGetAttribute(&nCU, hipDeviceAttributeMultiprocessorCount, dev);
  if (nCU <= 0) nCU = 256;
  int maxBlkPerCU = 0;
  hipOccupancyMaxActiveBlocksPerMultiprocessor(&maxBlkPerCU, process_kernel, TPB, 0);
  if (maxBlkPerCU < 1) maxBlkPerCU = 1;
  long long cap = (long long)nCU * (long long)maxBlkPerCU;
  int grid = (int)(cap < NBLK_MAX ? cap : NBLK_MAX);
  if (grid < 1) grid = nCU;

  hipError_t err = hipLaunchCooperativeKernel(process_kernel, dim3(grid), dim3(TPB),
                                              args, 0, stream);
  if (err != hipSuccess && grid > 256) {
    err = hipLaunchCooperativeKernel(process_kernel, dim3(256), dim3(TPB), args, 0, stream);
  }
  if (err != hipSuccess && grid > 128) {
    err = hipLaunchCooperativeKernel(process_kernel, dim3(128), dim3(TPB), args, 0, stream);
  }
}

// Round 5
// 693.403 us; speedup vs baseline: 1.1472x; 1.1472x over previous
//
#include <hip/hip_runtime.h>
#include <hip/hip_cooperative_groups.h>
#include <math.h>

namespace cg = cooperative_groups;

#define DD 128
#define G 4              // steps batched per block (same level => node-disjoint => race-free)
#define TPB 512
#define NBLK_MAX 512
#define SMAX 2048

__device__ __forceinline__ float sigmoidf(float x) { return 1.0f / (1.0f + expf(-x)); }

// ---------------------------------------------------------------------------
// Predecessor kernel: block j scans i<j for last step sharing a node.
// ---------------------------------------------------------------------------
__global__ __launch_bounds__(64) void pred_kernel(
    const int* __restrict__ heads, const int* __restrict__ tails, int S,
    int* __restrict__ ph, int* __restrict__ pt) {
  const int j = blockIdx.x;
  if (j >= S) return;
  const int myh = heads[j], myt = tails[j];
  const int lane = threadIdx.x;
  int mph = -1, mpt = -1;
#pragma unroll 4
  for (int i = lane; i < j; i += 64) {
    int a = heads[i], b = tails[i];
    if (a == myh || b == myh) mph = i;
    if (a == myt || b == myt) mpt = i;
  }
#pragma unroll
  for (int off = 32; off > 0; off >>= 1) {
    mph = max(mph, __shfl_down(mph, off));
    mpt = max(mpt, __shfl_down(mpt, off));
  }
  if (lane == 0) { ph[j] = mph; pt[j] = mpt; }
}

// ---------------------------------------------------------------------------
// Finalize: fixpoint level relaxation + bucket by level.
// ---------------------------------------------------------------------------
__global__ __launch_bounds__(1024) void finalize_kernel(
    int S, const int* __restrict__ phg, const int* __restrict__ ptg,
    int* __restrict__ order, int* __restrict__ level_off, int* __restrict__ n_levels) {
  __shared__ int lvl[SMAX], ph[SMAX], pt[SMAX], cnt[SMAX];
  __shared__ int changed, maxl;
  const int tid = threadIdx.x;

  for (int j = tid; j < S; j += 1024) { ph[j] = phg[j]; pt[j] = ptg[j]; lvl[j] = 1; }
  __syncthreads();

  for (int it = 0; it < S + 2; ++it) {
    if (tid == 0) changed = 0;
    __syncthreads();
    for (int j = tid; j < S; j += 1024) {
      int l = 1;
      int a = ph[j]; if (a >= 0) l = lvl[a] + 1;
      int b = pt[j]; if (b >= 0) { int lb = lvl[b] + 1; if (lb > l) l = lb; }
      if (l != lvl[j]) { lvl[j] = l; changed = 1; }
    }
    __syncthreads();
    if (!changed) break;
    __syncthreads();
  }

  if (tid == 0) maxl = 0;
  __syncthreads();
  for (int j = tid; j < S; j += 1024) atomicMax(&maxl, lvl[j]);
  __syncthreads();
  const int M = maxl;

  for (int l = tid; l < M; l += 1024) cnt[l] = 0;
  __syncthreads();
  for (int j = tid; j < S; j += 1024) atomicAdd(&cnt[lvl[j] - 1], 1);
  __syncthreads();
  if (tid == 0) {
    int run = 0;
    level_off[0] = 0;
    for (int l = 0; l < M; ++l) { run += cnt[l]; level_off[l + 1] = run; }
    n_levels[0] = M;
  }
  __syncthreads();

  for (int l = tid; l < M; l += 1024) cnt[l] = 0;
  __syncthreads();
  for (int j = tid; j < S; j += 1024) {
    int lv = lvl[j] - 1;
    int pos = level_off[lv] + atomicAdd(&cnt[lv], 1);
    order[pos] = j;
  }
}

// ---------------------------------------------------------------------------
// Process kernel: G=4 same-level steps per block.
// R5 change: every weight loop starts at a per-block staggered offset d0
// (spreads concurrent blocks across 128 distinct L2 lines per matrix instead
// of all queueing on the SAME line in lockstep -> measured ~2000cyc effective
// latency in R4) and is unrolled x8 for deep memory-level parallelism.
// ---------------------------------------------------------------------------
struct PParams {
  const int* heads; const int* tails; const float* times;
  float* node_rep; float* cell_head; float* hidden_head; float* cell_tail; float* hidden_tail;
  const float* Weh1; const float* Weh2; const float* beh;
  const float* Wet1; const float* Wet2; const float* bet;
  const float* Wxh; const float* Whh; const float* bh; const float* Wdh; const float* bdh;
  const float* Wxt; const float* Wht; const float* bt; const float* Wdt; const float* bdt;
  const float* Wc1; const float* Wc2;
  float* out; float* rt;
  const int* order; const int* level_off; const int* n_levels;
  int S;
};

__global__ __launch_bounds__(TPB) void process_kernel(PParams p) {
  cg::grid_group grid = cg::this_grid();
  const int tid = threadIdx.x;
  const int d0 = (int)((blockIdx.x * 37u) & 127u);   // per-block stagger (wave-uniform)

  __shared__ __align__(16) float S_[12288];   // 48 KB
  __shared__ int sIdx[G], hIdx[G], tIdx[G];
  __shared__ float tmv[G], decHs[G], decTs[G];

  const int O_REPH = 0,    O_REPT = 1024, O_CHS = 2048, O_CTS = 3072;  // dead after A
  const int O_ZH   = 0,    O_ZT   = 2048;                              // born in B (overlay)
  const int O_HHS  = 4096, O_HTS  = 5120, O_HTH = 6144, O_HHT = 7168;  // persistent
  const int O_EH   = 8192, O_ET   = 9216;                              // edge (A..B) == nh (C..D)
  const int O_CAH  = 10240, O_CAT = 11264;                             // cadj (A..C)

  int nlv = p.n_levels[0];
  if (nlv < 0) nlv = 0;
  if (nlv > SMAX) nlv = SMAX;

  for (int lv = 0; lv < nlv; ++lv) {
    const int beg = p.level_off[lv], end = p.level_off[lv + 1];
    const int Lsz = end - beg;
    int gE = (Lsz + (int)gridDim.x - 1) / (int)gridDim.x;
    if (gE > G) gE = G;
    if (gE < 1) gE = 1;

    for (int base = beg + (int)blockIdx.x * gE; base < end; base += (int)gridDim.x * gE) {
      const int ng = min(gE, end - base);
      __syncthreads();
      if (tid < ng) {
        int s = p.order[base + tid]; sIdx[tid] = s;
        int h = p.heads[s], t = p.tails[s];
        hIdx[tid] = h; tIdx[tid] = t;
        float tm = p.times[s]; tmv[tid] = tm;
        decHs[tid] = expf(-(tm - p.rt[h]));
        decTs[tid] = expf(-(tm - p.rt[t]));
      }
      __syncthreads();

      // -------- Gather: 8 node rows per step into [d][G] LDS + emit outputs
      {
        const int g = tid >> 7, d = tid & 127;
        if (g < ng) {
          const size_t oh = (size_t)hIdx[g] * DD + d;
          const size_t ot = (size_t)tIdx[g] * DD + d;
          const int b = d * 8 + g;
          float rh = p.node_rep[oh];
          S_[O_REPH + b] = rh; p.out[(size_t)sIdx[g] * DD + d] = rh;
          S_[O_CHS + b] = p.cell_head[oh];
          S_[O_HHS + b] = p.hidden_head[oh];
          S_[O_HTH + b] = p.hidden_tail[oh];
          float rt_ = p.node_rep[ot];
          S_[O_REPT + b] = rt_; p.out[(size_t)(p.S + sIdx[g]) * DD + d] = rt_;
          S_[O_CTS + b] = p.cell_tail[ot];
          S_[O_HTS + b] = p.hidden_tail[ot];
          S_[O_HHT + b] = p.hidden_head[ot];
        }
      }
      __syncthreads();

      // -------- Phase A: edges (roles 0,1) + decayed cell adjust (roles 2,3)
      {
        const int role = tid >> 7, e = tid & 127;
        if (role == 0) {
          float a0 = p.beh[e], a1 = a0, a2 = a0, a3 = a0;
#pragma unroll 8
          for (int i = 0; i < DD; ++i) {
            const int d = (i + d0) & 127;
            float w1 = p.Weh1[d * DD + e], w2 = p.Weh2[d * DD + e];
            float4 rh = *(const float4*)&S_[O_REPH + d * 8];
            float4 rt4 = *(const float4*)&S_[O_REPT + d * 8];
            a0 += rh.x * w1 + rt4.x * w2; a1 += rh.y * w1 + rt4.y * w2;
            a2 += rh.z * w1 + rt4.z * w2; a3 += rh.w * w1 + rt4.w * w2;
          }
          float4 o; o.x = tanhf(a0); o.y = tanhf(a1); o.z = tanhf(a2); o.w = tanhf(a3);
          *(float4*)&S_[O_EH + e * 8] = o;
        } else if (role == 1) {
          float a0 = p.bet[e], a1 = a0, a2 = a0, a3 = a0;
#pragma unroll 8
          for (int i = 0; i < DD; ++i) {
            const int d = (i + d0) & 127;
            float w1 = p.Wet1[d * DD + e], w2 = p.Wet2[d * DD + e];
            float4 rh = *(const float4*)&S_[O_REPH + d * 8];
            float4 rt4 = *(const float4*)&S_[O_REPT + d * 8];
            a0 += rh.x * w1 + rt4.x * w2; a1 += rh.y * w1 + rt4.y * w2;
            a2 += rh.z * w1 + rt4.z * w2; a3 += rh.w * w1 + rt4.w * w2;
          }
          float4 o; o.x = tanhf(a0); o.y = tanhf(a1); o.z = tanhf(a2); o.w = tanhf(a3);
          *(float4*)&S_[O_ET + e * 8] = o;
        } else if (role == 2) {
          float a0 = p.bdh[e], a1 = a0, a2 = a0, a3 = a0;
#pragma unroll 8
          for (int i = 0; i < DD; ++i) {
            const int d = (i + d0) & 127;
            float wd = p.Wdh[d * DD + e];
            float4 c4 = *(const float4*)&S_[O_CHS + d * 8];
            a0 += c4.x * wd; a1 += c4.y * wd; a2 += c4.z * wd; a3 += c4.w * wd;
          }
          float cs0 = tanhf(a0), cs1 = tanhf(a1), cs2 = tanhf(a2), cs3 = tanhf(a3);
          float4 o;
          o.x = S_[O_CHS + e * 8 + 0] - cs0 + cs0 * decHs[0];
          o.y = S_[O_CHS + e * 8 + 1] - cs1 + cs1 * decHs[1];
          o.z = S_[O_CHS + e * 8 + 2] - cs2 + cs2 * decHs[2];
          o.w = S_[O_CHS + e * 8 + 3] - cs3 + cs3 * decHs[3];
          *(float4*)&S_[O_CAH + e * 8] = o;
        } else {
          float a0 = p.bdt[e], a1 = a0, a2 = a0, a3 = a0;
#pragma unroll 8
          for (int i = 0; i < DD; ++i) {
            const int d = (i + d0) & 127;
            float wd = p.Wdt[d * DD + e];
            float4 c4 = *(const float4*)&S_[O_CTS + d * 8];
            a0 += c4.x * wd; a1 += c4.y * wd; a2 += c4.z * wd; a3 += c4.w * wd;
          }
          float cs0 = tanhf(a0), cs1 = tanhf(a1), cs2 = tanhf(a2), cs3 = tanhf(a3);
          float4 o;
          o.x = S_[O_CTS + e * 8 + 0] - cs0 + cs0 * decTs[0];
          o.y = S_[O_CTS + e * 8 + 1] - cs1 + cs1 * decTs[1];
          o.z = S_[O_CTS + e * 8 + 2] - cs2 + cs2 * decTs[2];
          o.w = S_[O_CTS + e * 8 + 3] - cs3 + cs3 * decTs[3];
          *(float4*)&S_[O_CAT + e * 8] = o;
        }
      }
      __syncthreads();

      // -------- Phase B: z = x@Wx + h@Wh + b, both sides, 1 col/thread, G accs
      {
        const int c = tid;
        float h0 = p.bh[c], h1 = h0, h2 = h0, h3 = h0;
        float t0 = p.bt[c], t1 = t0, t2 = t0, t3 = t0;
#pragma unroll 8
        for (int i = 0; i < DD; ++i) {
          const int d = (i + d0) & 127;
          float wxh = p.Wxh[d * 512 + c], whh = p.Whh[d * 512 + c];
          float wxt = p.Wxt[d * 512 + c], wht = p.Wht[d * 512 + c];
          float4 ex = *(const float4*)&S_[O_EH + d * 8];
          float4 hx = *(const float4*)&S_[O_HHS + d * 8];
          float4 et = *(const float4*)&S_[O_ET + d * 8];
          float4 ht4 = *(const float4*)&S_[O_HTS + d * 8];
          h0 += ex.x * wxh + hx.x * whh; h1 += ex.y * wxh + hx.y * whh;
          h2 += ex.z * wxh + hx.z * whh; h3 += ex.w * wxh + hx.w * whh;
          t0 += et.x * wxt + ht4.x * wht; t1 += et.y * wxt + ht4.y * wht;
          t2 += et.z * wxt + ht4.z * wht; t3 += et.w * wxt + ht4.w * wht;
        }
        float4 zh; zh.x = h0; zh.y = h1; zh.z = h2; zh.w = h3;
        float4 zt; zt.x = t0; zt.y = t1; zt.z = t2; zt.w = t3;
        *(float4*)&S_[O_ZH + c * 4] = zh;
        *(float4*)&S_[O_ZT + c * 4] = zt;
      }
      __syncthreads();

      // -------- Phase C: gates, c/h update, scatter state, rt update
      {
        const int side = tid >> 8, sub = (tid >> 7) & 1, e = tid & 127;
        const int zo = side ? O_ZT : O_ZH;
        const int co = side ? O_CAT : O_CAH;
        const int no = side ? O_ET : O_EH;
        float* ctab = side ? p.cell_tail : p.cell_head;
        float* htab = side ? p.hidden_tail : p.hidden_head;
        for (int q = 0; q < 2; ++q) {
          int g = sub + 2 * q;
          if (g >= ng) continue;
          float iv = sigmoidf(S_[zo + e * 4 + g]);
          float fv = sigmoidf(S_[zo + (128 + e) * 4 + g]);
          float ov = sigmoidf(S_[zo + (256 + e) * 4 + g]);
          float gv = tanhf(S_[zo + (384 + e) * 4 + g]);
          float cadj = S_[co + e * 8 + g];
          float cn = fv * cadj + iv * gv;
          float hn = ov * tanhf(cn);
          S_[no + e * 8 + g] = hn;
          int node = side ? tIdx[g] : hIdx[g];
          ctab[(size_t)node * DD + e] = cn;
          htab[(size_t)node * DD + e] = hn;
        }
        if (tid < 2 * G) {
          int g = tid & (G - 1);
          if (g < ng) p.rt[(tid >= G) ? tIdx[g] : hIdx[g]] = tmv[g];
        }
      }
      __syncthreads();

      // -------- Phase D: combiner, rep scatter (tail wins on h==t)
      {
        const int role = tid >> 7, e = tid & 127;
        if (role == 0) {
          float a0 = 0.f, a1 = 0.f, a2 = 0.f, a3 = 0.f;
#pragma unroll 8
          for (int i = 0; i < DD; ++i) {
            const int d = (i + d0) & 127;
            float w1 = p.Wc1[d * DD + e], w2 = p.Wc2[d * DD + e];
            float4 x = *(const float4*)&S_[O_EH + d * 8];    // nhH
            float4 y = *(const float4*)&S_[O_HTH + d * 8];   // old hidden_tail[h]
            a0 += x.x * w1 + y.x * w2; a1 += x.y * w1 + y.y * w2;
            a2 += x.z * w1 + y.z * w2; a3 += x.w * w1 + y.w * w2;
          }
          float r[4] = {a0, a1, a2, a3};
          for (int g = 0; g < ng; ++g)
            if (hIdx[g] != tIdx[g])
              p.node_rep[(size_t)hIdx[g] * DD + e] = tanhf(r[g]);
        } else if (role == 1) {
          float a0 = 0.f, a1 = 0.f, a2 = 0.f, a3 = 0.f;
#pragma unroll 8
          for (int i = 0; i < DD; ++i) {
            const int d = (i + d0) & 127;
            float w1 = p.Wc1[d * DD + e], w2 = p.Wc2[d * DD + e];
            float4 x = *(const float4*)&S_[O_HHT + d * 8];   // old hidden_head[t] @ Wc1
            float4 y = *(const float4*)&S_[O_ET + d * 8];    // nhT @ Wc2
            a0 += x.x * w1 + y.x * w2; a1 += x.y * w1 + y.y * w2;
            a2 += x.z * w1 + y.z * w2; a3 += x.w * w1 + y.w * w2;
          }
          float r[4] = {a0, a1, a2, a3};
          for (int g = 0; g < ng; ++g)
            p.node_rep[(size_t)tIdx[g] * DD + e] = tanhf(r[g]);
        }
      }
    }
    __threadfence();
    grid.sync();
  }
}

// ---------------------------------------------------------------------------
extern "C" void kernel_launch(void* const* d_in, const int* in_sizes, int n_in,
                              void* d_out, int out_size, void* d_ws, size_t ws_size,
                              hipStream_t stream) {
  const int* heads = (const int*)d_in[0];
  const int* tails = (const int*)d_in[1];
  const float* times = (const float*)d_in[2];
  float* node_rep    = (float*)d_in[3];
  float* cell_head   = (float*)d_in[4];
  float* hidden_head = (float*)d_in[5];
  float* cell_tail   = (float*)d_in[6];
  float* hidden_tail = (float*)d_in[7];
  const float* Weh1 = (const float*)d_in[8];
  const float* Weh2 = (const float*)d_in[9];
  const float* beh  = (const float*)d_in[10];
  const float* Wet1 = (const float*)d_in[11];
  const float* Wet2 = (const float*)d_in[12];
  const float* bet  = (const float*)d_in[13];
  const float* Wxh  = (const float*)d_in[14];
  const float* Whh  = (const float*)d_in[15];
  const float* bh   = (const float*)d_in[16];
  const float* Wdh  = (const float*)d_in[17];
  const float* bdh  = (const float*)d_in[18];
  const float* Wxt  = (const float*)d_in[19];
  const float* Wht  = (const float*)d_in[20];
  const float* bt   = (const float*)d_in[21];
  const float* Wdt  = (const float*)d_in[22];
  const float* bdt  = (const float*)d_in[23];
  const float* Wc1  = (const float*)d_in[24];
  const float* Wc2  = (const float*)d_in[25];

  const int S = in_sizes[0];
  const int N = in_sizes[3] / DD;

  char* ws = (char*)d_ws;
  float* rt = (float*)ws;
  size_t rtBytes = (((size_t)N * 4) + 511) & ~(size_t)511;
  int* order     = (int*)(ws + rtBytes);
  int* level_off = order + SMAX;
  int* n_levels  = level_off + SMAX + 1;
  int* ph        = n_levels + 64;
  int* pt        = ph + SMAX;

  hipMemsetAsync(rt, 0, (size_t)N * 4, stream);
  pred_kernel<<<S, 64, 0, stream>>>(heads, tails, S, ph, pt);
  finalize_kernel<<<1, 1024, 0, stream>>>(S, ph, pt, order, level_off, n_levels);

  PParams p;
  p.heads = heads; p.tails = tails; p.times = times;
  p.node_rep = node_rep; p.cell_head = cell_head; p.hidden_head = hidden_head;
  p.cell_tail = cell_tail; p.hidden_tail = hidden_tail;
  p.Weh1 = Weh1; p.Weh2 = Weh2; p.beh = beh;
  p.Wet1 = Wet1; p.Wet2 = Wet2; p.bet = bet;
  p.Wxh = Wxh; p.Whh = Whh; p.bh = bh; p.Wdh = Wdh; p.bdh = bdh;
  p.Wxt = Wxt; p.Wht = Wht; p.bt = bt; p.Wdt = Wdt; p.bdt = bdt;
  p.Wc1 = Wc1; p.Wc2 = Wc2;
  p.out = (float*)d_out; p.rt = rt;
  p.order = order; p.level_off = level_off; p.n_levels = n_levels;
  p.S = S;

  void* args[] = { (void*)&p };

  int dev = 0; hipGetDevice(&dev);
  int nCU = 0;
  hipDeviceGetAttribute(&nCU, hipDeviceAttributeMultiprocessorCount, dev);
  if (nCU <= 0) nCU = 256;
  int maxBlkPerCU = 0;
  hipOccupancyMaxActiveBlocksPerMultiprocessor(&maxBlkPerCU, process_kernel, TPB, 0);
  if (maxBlkPerCU < 1) maxBlkPerCU = 1;
  long long cap = (long long)nCU * (long long)maxBlkPerCU;
  int grid = (int)(cap < NBLK_MAX ? cap : NBLK_MAX);
  if (grid < 1) grid = nCU;

  hipError_t err = hipLaunchCooperativeKernel(process_kernel, dim3(grid), dim3(TPB),
                                              args, 0, stream);
  if (err != hipSuccess && grid > 256) {
    err = hipLaunchCooperativeKernel(process_kernel, dim3(256), dim3(TPB), args, 0, stream);
  }
  if (err != hipSuccess && grid > 128) {
    err = hipLaunchCooperativeKernel(process_kernel, dim3(128), dim3(TPB), args, 0, stream);
  }
}